// Round 2
// baseline (1118.147 us; speedup 1.0000x reference)
//
#include <hip/hip_runtime.h>
#include <math.h>

// Problem constants (fixed by the reference).
constexpr int Bb = 8;
constexpr int Cc = 256;
constexpr int Hh = 4;
constexpr int Nn = 2048;
constexpr int Mm = 2048;
constexpr int Dd = 64;          // head dim
constexpr size_t BCN = (size_t)Bb * Cc * Nn;   // 4,194,304 elements

// ---------------------------------------------------------------------------
// Generic 1x1-conv (per-position GEMM): Y[b,o,n] = sum_i W[o,i] * X[b,i,n] + bias[o]
// Optional: * scale[b,n] (weight_v), BN+ReLU epilogue, residual add.
// Thread = one n, 8 consecutive o. W reads are block-uniform -> scalar loads.
// ---------------------------------------------------------------------------
template<int CIN1, int CIN2, int COUT, bool SCALE, bool BNRELU, bool RESID>
__global__ __launch_bounds__(256) void proj_kernel(
    const float* __restrict__ X1, const float* __restrict__ X2,
    const float* __restrict__ W, const float* __restrict__ bias,
    const float* __restrict__ scl,
    const float* __restrict__ bng, const float* __restrict__ bnb,
    const float* __restrict__ bnm, const float* __restrict__ bnv,
    const float* __restrict__ resid,
    float* __restrict__ Y, int NP)
{
  constexpr int CT = CIN1 + CIN2;
  const int n  = blockIdx.x * 256 + threadIdx.x;
  const int o0 = blockIdx.y * 8;
  const int b  = blockIdx.z;

  float acc[8] = {0.f,0.f,0.f,0.f,0.f,0.f,0.f,0.f};
  {
    const float* x = X1 + (size_t)b * CIN1 * NP + n;
    const float* w = W + (size_t)o0 * CT;
    #pragma unroll 4
    for (int i = 0; i < CIN1; ++i) {
      float xv = x[(size_t)i * NP];
      #pragma unroll
      for (int j = 0; j < 8; ++j) acc[j] = fmaf(w[j*CT + i], xv, acc[j]);
    }
  }
  if constexpr (CIN2 > 0) {
    const float* x = X2 + (size_t)b * CIN2 * NP + n;
    const float* w = W + (size_t)o0 * CT + CIN1;
    #pragma unroll 4
    for (int i = 0; i < CIN2; ++i) {
      float xv = x[(size_t)i * NP];
      #pragma unroll
      for (int j = 0; j < 8; ++j) acc[j] = fmaf(w[j*CT + i], xv, acc[j]);
    }
  }
  float sc = 1.0f;
  if constexpr (SCALE) sc = scl[(size_t)b * NP + n];
  #pragma unroll
  for (int j = 0; j < 8; ++j) {
    const int o = o0 + j;
    float r = acc[j] + bias[o];
    if constexpr (SCALE) r *= sc;                     // v = (Wv x + bv) * weight_v
    if constexpr (BNRELU) {
      float inv = bng[o] / sqrtf(bnv[o] + 1e-5f);
      r = fmaxf(r * inv + (bnb[o] - bnm[o] * inv), 0.f);
    }
    if constexpr (RESID) r += resid[((size_t)b * COUT + o) * NP + n];
    Y[((size_t)b * COUT + o) * NP + n] = r;
  }
}

// ---------------------------------------------------------------------------
// Flash attention (f32, online softmax). Q,K,V,O layout [B*H, D=64, N/M].
// Block = one (b,h), 64 query cols (BN=64), loop m in BM=64 tiles.
// 256 threads; thread = 4x4 register tile. LDS: Qs + (Ks|PsT union) + VsT,
// pad 68 so float4 rows stay 16B-aligned; 51 KB -> 3 blocks/CU.
// ---------------------------------------------------------------------------
constexpr int PADh = 68;

__global__ __launch_bounds__(256) void attn_kernel(
    const float* __restrict__ Q, const float* __restrict__ K,
    const float* __restrict__ V, float* __restrict__ O)
{
  __shared__ __align__(16) float Qs[Dd][PADh];    // [d][n_local]; reused for O at end
  __shared__ __align__(16) float KP[64][PADh];    // phase A: Ks[d][m]; phase B: PsT[m][n]
  __shared__ __align__(16) float VsT[64][PADh];   // [m][d]

  const int t   = threadIdx.x;
  const int bh  = blockIdx.y;
  const int n0  = blockIdx.x * 64;
  const int tn4 = (t >> 4) * 4;   // n-tile base (rows of S); wave w owns rows 16w..16w+15
  const int tm4 = (t & 15) * 4;   // m-tile base (phase1) / d base (phase2)
  const int c   = t & 63;
  const int r0  = t >> 6;

  const float* Qg = Q + (size_t)bh * Dd * Nn + n0;
  const float* Kg = K + (size_t)bh * Dd * Mm;
  const float* Vg = V + (size_t)bh * Dd * Mm;

  #pragma unroll
  for (int j = 0; j < 16; ++j) {
    int d = r0 + 4*j;
    Qs[d][c] = Qg[(size_t)d * Nn + c];
  }

  float accO[4][4] = {};                       // O[d=tm4+bd][n=tn4+an]
  float rowM[4] = {-1e30f,-1e30f,-1e30f,-1e30f};
  float rowL[4] = {0.f,0.f,0.f,0.f};

  for (int m0 = 0; m0 < Mm; m0 += 64) {
    __syncthreads();                           // prev phase2 done with KP/VsT
    #pragma unroll
    for (int j = 0; j < 16; ++j) {
      int d = r0 + 4*j;
      KP[d][c]  = Kg[(size_t)d * Mm + m0 + c];
      VsT[c][d] = Vg[(size_t)d * Mm + m0 + c];
    }
    __syncthreads();

    // S[tn4+a][tm4+b] = sum_d Q[d][n] * K[d][m]
    float s[4][4] = {};
    #pragma unroll 8
    for (int d = 0; d < Dd; ++d) {
      float4 qv = *(const float4*)(&Qs[d][tn4]);
      float4 kv = *(const float4*)(&KP[d][tm4]);
      const float qa[4] = {qv.x,qv.y,qv.z,qv.w};
      const float kb[4] = {kv.x,kv.y,kv.z,kv.w};
      #pragma unroll
      for (int a = 0; a < 4; ++a)
        #pragma unroll
        for (int b2 = 0; b2 < 4; ++b2)
          s[a][b2] = fmaf(qa[a], kb[b2], s[a][b2]);
    }

    // online softmax over m (row = lane group of 16, shfl_xor reduce)
    float corr[4];
    #pragma unroll
    for (int a = 0; a < 4; ++a) {
      #pragma unroll
      for (int b2 = 0; b2 < 4; ++b2) s[a][b2] *= 0.125f;   // 1/sqrt(64)
      float rm = fmaxf(fmaxf(s[a][0], s[a][1]), fmaxf(s[a][2], s[a][3]));
      #pragma unroll
      for (int msk = 1; msk < 16; msk <<= 1) rm = fmaxf(rm, __shfl_xor(rm, msk, 64));
      float nm = fmaxf(rowM[a], rm);
      corr[a] = __expf(rowM[a] - nm);
      float rs = 0.f;
      #pragma unroll
      for (int b2 = 0; b2 < 4; ++b2) { s[a][b2] = __expf(s[a][b2] - nm); rs += s[a][b2]; }
      #pragma unroll
      for (int msk = 1; msk < 16; msk <<= 1) rs += __shfl_xor(rs, msk, 64);
      rowL[a] = rowL[a] * corr[a] + rs;
      rowM[a] = nm;
    }
    #pragma unroll
    for (int bd = 0; bd < 4; ++bd)
      #pragma unroll
      for (int an = 0; an < 4; ++an) accO[bd][an] *= corr[an];

    __syncthreads();                           // everyone done reading Ks
    #pragma unroll
    for (int b2 = 0; b2 < 4; ++b2) {           // PsT[m][n] = P[n][m]
      float4 pv = make_float4(s[0][b2], s[1][b2], s[2][b2], s[3][b2]);
      *(float4*)(&KP[tm4 + b2][tn4]) = pv;
    }
    __syncthreads();

    // O[d][n] += sum_m V[d][m] * P[n][m]
    #pragma unroll 8
    for (int m = 0; m < 64; ++m) {
      float4 vv = *(const float4*)(&VsT[m][tm4]);
      float4 pv = *(const float4*)(&KP[m][tn4]);
      const float vb[4] = {vv.x,vv.y,vv.z,vv.w};
      const float pa[4] = {pv.x,pv.y,pv.z,pv.w};
      #pragma unroll
      for (int bd = 0; bd < 4; ++bd)
        #pragma unroll
        for (int an = 0; an < 4; ++an)
          accO[bd][an] = fmaf(vb[bd], pa[an], accO[bd][an]);
    }
  }

  float invl[4];
  #pragma unroll
  for (int an = 0; an < 4; ++an) invl[an] = 1.f / rowL[an];
  __syncthreads();
  #pragma unroll
  for (int bd = 0; bd < 4; ++bd) {             // stage O to LDS for coalesced writeout
    float4 ov = make_float4(accO[bd][0]*invl[0], accO[bd][1]*invl[1],
                            accO[bd][2]*invl[2], accO[bd][3]*invl[3]);
    *(float4*)(&Qs[tm4 + bd][tn4]) = ov;
  }
  __syncthreads();
  float* Og = O + (size_t)bh * Dd * Nn + n0;
  #pragma unroll
  for (int j = 0; j < 16; ++j) {
    int d = r0 + 4*j;
    Og[(size_t)d * Nn + c] = Qs[d][c];
  }
}

// ---------------------------------------------------------------------------
extern "C" void kernel_launch(void* const* d_in, const int* in_sizes, int n_in,
                              void* d_out, int out_size, void* d_ws, size_t ws_size,
                              hipStream_t stream)
{
  (void)in_sizes; (void)n_in; (void)out_size; (void)ws_size;
  const float* desc1 = (const float*)d_in[0];
  const float* desc2 = (const float*)d_in[1];
  const float* wvv   = (const float*)d_in[2];
  const float* Wq  = (const float*)d_in[3];  const float* bq  = (const float*)d_in[4];
  const float* Wk  = (const float*)d_in[5];  const float* bk  = (const float*)d_in[6];
  const float* Wv  = (const float*)d_in[7];  const float* bv  = (const float*)d_in[8];
  const float* Wm  = (const float*)d_in[9];  const float* bm  = (const float*)d_in[10];
  const float* Wc1 = (const float*)d_in[11]; const float* bc1 = (const float*)d_in[12];
  const float* bng = (const float*)d_in[13]; const float* bnb = (const float*)d_in[14];
  const float* bnm = (const float*)d_in[15]; const float* bnv = (const float*)d_in[16];
  const float* Wc2 = (const float*)d_in[17]; const float* bc2 = (const float*)d_in[18];
  float* out = (float*)d_out;

  // Workspace layout (floats). Aliasing is safe: each stage's input is dead
  // before its buffer is reused as an output. Peak: 4*BCN*4B = 64 MB.
  float* ws   = (float*)d_ws;
  float* q    = ws;                 // [B,C,N]
  float* k    = ws + BCN;           // [B,C,M]
  float* v    = ws + 2*BCN;         // [B,C,M]
  float* attn = ws + 3*BCN;         // [B,C,N]
  float* mout = q;                  // reuse q after attention
  float* h    = k;                  // [B,2C,N] reuses k+v after attention

  dim3 blk(256);
  // q = Wq*desc1 + bq
  proj_kernel<256,0,256,false,false,false><<<dim3(Nn/256, 32, Bb), blk, 0, stream>>>(
      desc1, nullptr, Wq, bq, nullptr, nullptr,nullptr,nullptr,nullptr, nullptr, q, Nn);
  // k = Wk*desc2 + bk
  proj_kernel<256,0,256,false,false,false><<<dim3(Mm/256, 32, Bb), blk, 0, stream>>>(
      desc2, nullptr, Wk, bk, nullptr, nullptr,nullptr,nullptr,nullptr, nullptr, k, Mm);
  // v = (Wv*desc2 + bv) * weight_v[b,m]
  proj_kernel<256,0,256,true,false,false><<<dim3(Mm/256, 32, Bb), blk, 0, stream>>>(
      desc2, nullptr, Wv, bv, wvv, nullptr,nullptr,nullptr,nullptr, nullptr, v, Mm);
  // attn = softmax(q^T k / 8) @ v^T   per (b,h)
  attn_kernel<<<dim3(Nn/64, Bb*Hh), blk, 0, stream>>>(q, k, v, attn);
  // mout = Wm*attn + bm
  proj_kernel<256,0,256,false,false,false><<<dim3(Nn/256, 32, Bb), blk, 0, stream>>>(
      attn, nullptr, Wm, bm, nullptr, nullptr,nullptr,nullptr,nullptr, nullptr, mout, Nn);
  // h = relu(BN(Wc1*[desc1; mout] + bc1))
  proj_kernel<256,256,512,false,true,false><<<dim3(Nn/256, 64, Bb), blk, 0, stream>>>(
      desc1, mout, Wc1, bc1, nullptr, bng,bnb,bnm,bnv, nullptr, h, Nn);
  // out = desc1 + Wc2*h + bc2
  proj_kernel<512,0,256,false,false,true><<<dim3(Nn/256, 32, Bb), blk, 0, stream>>>(
      h, nullptr, Wc2, bc2, nullptr, nullptr,nullptr,nullptr,nullptr, desc1, out, Nn);
}

// Round 5
// 654.535 us; speedup vs baseline: 1.7083x; 1.7083x over previous
//
#include <hip/hip_runtime.h>
#include <hip/hip_bf16.h>
#include <math.h>

// Problem constants (fixed by the reference).
constexpr int Bb = 8;
constexpr int Cc = 256;
constexpr int Hh = 4;
constexpr int Nn = 2048;
constexpr int Mm = 2048;
constexpr int Dd = 64;          // head dim
constexpr size_t BCN = (size_t)Bb * Cc * Nn;   // 4,194,304 elements

typedef __attribute__((ext_vector_type(8))) short short8;
typedef __attribute__((ext_vector_type(4))) float f32x4;
typedef __attribute__((ext_vector_type(8))) unsigned short ushort8;

__device__ __forceinline__ unsigned short bfu(float x) {
  __hip_bfloat16 b = __float2bfloat16(x);        // RNE
  return __builtin_bit_cast(unsigned short, b);
}

// ---------------------------------------------------------------------------
// Generic 1x1-conv: Y[b,o,n] = sum_i W[o,i] X[b,i,n] + bias[o], epilogues.
// OMODE: 0 = f32 natural [b][o][n]; 1 = bf16 natural (v path);
//        2 = bf16 head-transposed [b*H+h][n][d] (q/k path for MFMA frags).
// ---------------------------------------------------------------------------
template<int CIN1, int CIN2, int COUT, bool SCALE, bool BNRELU, bool RESID, int OMODE>
__global__ __launch_bounds__(256) void proj_kernel(
    const float* __restrict__ X1, const float* __restrict__ X2,
    const float* __restrict__ W, const float* __restrict__ bias,
    const float* __restrict__ scl,
    const float* __restrict__ bng, const float* __restrict__ bnb,
    const float* __restrict__ bnm, const float* __restrict__ bnv,
    const float* __restrict__ resid,
    void* __restrict__ Yv, int NP, float oscale)
{
  constexpr int CT = CIN1 + CIN2;
  const int n  = blockIdx.x * 256 + threadIdx.x;
  const int o0 = blockIdx.y * 8;
  const int b  = blockIdx.z;

  float acc[8] = {0.f,0.f,0.f,0.f,0.f,0.f,0.f,0.f};
  {
    const float* x = X1 + (size_t)b * CIN1 * NP + n;
    const float* w = W + (size_t)o0 * CT;
    #pragma unroll 4
    for (int i = 0; i < CIN1; ++i) {
      float xv = x[(size_t)i * NP];
      #pragma unroll
      for (int j = 0; j < 8; ++j) acc[j] = fmaf(w[j*CT + i], xv, acc[j]);
    }
  }
  if constexpr (CIN2 > 0) {
    const float* x = X2 + (size_t)b * CIN2 * NP + n;
    const float* w = W + (size_t)o0 * CT + CIN1;
    #pragma unroll 4
    for (int i = 0; i < CIN2; ++i) {
      float xv = x[(size_t)i * NP];
      #pragma unroll
      for (int j = 0; j < 8; ++j) acc[j] = fmaf(w[j*CT + i], xv, acc[j]);
    }
  }
  float sc = 1.0f;
  if constexpr (SCALE) sc = scl[(size_t)b * NP + n];

  float res[8];
  #pragma unroll
  for (int j = 0; j < 8; ++j) {
    const int o = o0 + j;
    float r = acc[j] + bias[o];
    if constexpr (SCALE) r *= sc;
    r *= oscale;
    if constexpr (BNRELU) {
      float inv = bng[o] / sqrtf(bnv[o] + 1e-5f);
      r = fmaxf(r * inv + (bnb[o] - bnm[o] * inv), 0.f);
    }
    if constexpr (RESID) r += resid[((size_t)b * COUT + o) * NP + n];
    res[j] = r;
  }

  if constexpr (OMODE == 0) {
    float* Y = (float*)Yv;
    #pragma unroll
    for (int j = 0; j < 8; ++j)
      Y[((size_t)b * COUT + (o0 + j)) * NP + n] = res[j];
  } else if constexpr (OMODE == 1) {
    unsigned short* Y = (unsigned short*)Yv;
    #pragma unroll
    for (int j = 0; j < 8; ++j)
      Y[((size_t)b * COUT + (o0 + j)) * NP + n] = bfu(res[j]);
  } else {
    // [b*H + h][n][d] bf16, 8 consecutive d -> one 16B store
    unsigned short* Y = (unsigned short*)Yv;
    const int hh = o0 >> 6, d0 = o0 & 63;
    ushort8 pk;
    #pragma unroll
    for (int j = 0; j < 8; ++j) pk[j] = bfu(res[j]);
    *(ushort8*)(&Y[(((size_t)b * Hh + hh) * NP + n) * 64 + d0]) = pk;
  }
}

// ---------------------------------------------------------------------------
// MFMA flash attention (bf16 in, f32 accum). Swapped QK^T: S^T = mfma(K^T, Q^T)
// so each lane holds all m of one n-column -> lane-local softmax reduce.
// Wave = 32 n-cols x all m; block = 4 independent waves (no barriers).
// Q/K/V fragments loaded straight from global (16B/lane contiguous); only P
// goes through per-wave XOR-swizzled LDS.
// Layouts: Qt/Kt = [bh][n|m][64] bf16 (q pre-scaled by 0.125), Vb = [bh][d][m].
// ---------------------------------------------------------------------------
__global__ __launch_bounds__(256) void attn_mfma_kernel(
    const unsigned short* __restrict__ Qt, const unsigned short* __restrict__ Kt,
    const unsigned short* __restrict__ Vb, float* __restrict__ O)
{
  // XCD-major decode: all 16 n-blocks of one bh land on one XCD's L2.
  const int id  = blockIdx.x;
  const int xcd = id & 7;
  const int s8  = id >> 3;            // 0..63
  const int bh  = xcd + 8 * (s8 >> 4);
  const int nb  = s8 & 15;
  const int wv  = threadIdx.x >> 6;
  const int l   = threadIdx.x & 63;
  const int c   = l & 15;
  const int h   = l >> 4;
  const int n0  = nb * 128 + wv * 32;

  const unsigned short* Qw = Qt + ((size_t)bh * Nn + n0) * 64;
  const unsigned short* Kb = Kt + (size_t)bh * Mm * 64;
  const unsigned short* Vw = Vb + (size_t)bh * 64 * Mm;

  __shared__ unsigned short Pl[4][32 * 64];     // per-wave P [32n][64m] bf16, swizzled
  char* P = (char*)Pl[wv];

  // Q B-frags (held in regs all loop): col n = j*16+c, k d = ks*32 + h*8 + i
  short8 qf[2][2];
  #pragma unroll
  for (int j = 0; j < 2; ++j)
    #pragma unroll
    for (int ks = 0; ks < 2; ++ks)
      qf[j][ks] = *(const short8*)(Qw + ((size_t)(j*16 + c)) * 64 + ks*32 + h*8);

  f32x4 acc[4][2];                    // O^ [dblk][j]; rows d, cols n
  #pragma unroll
  for (int d = 0; d < 4; ++d)
    #pragma unroll
    for (int j = 0; j < 2; ++j) acc[d][j] = (f32x4){0.f,0.f,0.f,0.f};
  float rowM[2] = {-1e30f, -1e30f};
  float rowL[2] = {0.f, 0.f};

  #pragma unroll 1
  for (int m0 = 0; m0 < Mm; m0 += 64) {
    // K A-frags: row m = m0+g*16+c, k d = ks*32 + h*8 + i
    short8 kf[4][2];
    #pragma unroll
    for (int g = 0; g < 4; ++g)
      #pragma unroll
      for (int ks = 0; ks < 2; ++ks)
        kf[g][ks] = *(const short8*)(Kb + ((size_t)(m0 + g*16 + c)) * 64 + ks*32 + h*8);

    // S^T[m][n]: lane holds col n = j*16+c, rows m = m0 + g*16 + h*4 + r
    f32x4 sc4[4][2];
    #pragma unroll
    for (int g = 0; g < 4; ++g)
      #pragma unroll
      for (int j = 0; j < 2; ++j) {
        f32x4 z = (f32x4){0.f,0.f,0.f,0.f};
        z = __builtin_amdgcn_mfma_f32_16x16x32_bf16(kf[g][0], qf[j][0], z, 0, 0, 0);
        z = __builtin_amdgcn_mfma_f32_16x16x32_bf16(kf[g][1], qf[j][1], z, 0, 0, 0);
        sc4[g][j] = z;
      }

    // Issue V A-frags now (independent of softmax -> latency hides under it).
    short8 vf[4][2];
    #pragma unroll
    for (int db = 0; db < 4; ++db)
      #pragma unroll
      for (int ks = 0; ks < 2; ++ks)
        vf[db][ks] = *(const short8*)(Vw + ((size_t)(db*16 + c)) * Mm + m0 + ks*32 + h*8);

    // Online softmax, lane-local over 16 m + shfl over h-lanes.
    #pragma unroll
    for (int j = 0; j < 2; ++j) {
      float mx = -1e30f;
      #pragma unroll
      for (int g = 0; g < 4; ++g)
        #pragma unroll
        for (int r = 0; r < 4; ++r) mx = fmaxf(mx, sc4[g][j][r]);
      mx = fmaxf(mx, __shfl_xor(mx, 16));
      mx = fmaxf(mx, __shfl_xor(mx, 32));
      float nm = fmaxf(rowM[j], mx);
      float corr = __expf(rowM[j] - nm);
      rowM[j] = nm;
      float sum = 0.f;
      #pragma unroll
      for (int g = 0; g < 4; ++g) {
        #pragma unroll
        for (int r = 0; r < 4; ++r) {
          float e = __expf(sc4[g][j][r] - nm);
          sc4[g][j][r] = e;
          sum += e;
        }
      }
      sum += __shfl_xor(sum, 16);
      sum += __shfl_xor(sum, 32);
      rowL[j] = rowL[j] * corr + sum;
      #pragma unroll
      for (int db = 0; db < 4; ++db)
        #pragma unroll
        for (int r = 0; r < 4; ++r) acc[db][j][r] *= corr;

      // P write: row n = j*16+c, 4 consecutive m = g*16 + h*4 + r -> b64
      #pragma unroll
      for (int g = 0; g < 4; ++g) {
        unsigned int lo = ((unsigned int)bfu(sc4[g][j][1]) << 16) | bfu(sc4[g][j][0]);
        unsigned int hi = ((unsigned int)bfu(sc4[g][j][3]) << 16) | bfu(sc4[g][j][2]);
        int off = (j*16 + c) * 128 + g*32 + h*8;
        off ^= (c & 7) << 4;
        *(uint2*)(P + off) = make_uint2(lo, hi);
      }
    }

    // PV: B-frags from P (col n = j*16+c, k m = ks*32 + h*8), A = V frags.
    #pragma unroll
    for (int j = 0; j < 2; ++j) {
      short8 pf[2];
      #pragma unroll
      for (int ks = 0; ks < 2; ++ks) {
        int off = (j*16 + c) * 128 + ks*64 + h*16;
        off ^= (c & 7) << 4;
        pf[ks] = *(const short8*)(P + off);
      }
      #pragma unroll
      for (int db = 0; db < 4; ++db) {
        acc[db][j] = __builtin_amdgcn_mfma_f32_16x16x32_bf16(vf[db][0], pf[0], acc[db][j], 0, 0, 0);
        acc[db][j] = __builtin_amdgcn_mfma_f32_16x16x32_bf16(vf[db][1], pf[1], acc[db][j], 0, 0, 0);
      }
    }
  }

  const float invl[2] = {1.f / rowL[0], 1.f / rowL[1]};
  float* Og = O + ((size_t)bh * 64) * Nn + n0;
  #pragma unroll
  for (int db = 0; db < 4; ++db)
    #pragma unroll
    for (int j = 0; j < 2; ++j)
      #pragma unroll
      for (int r = 0; r < 4; ++r)
        Og[(size_t)(db*16 + h*4 + r) * Nn + j*16 + c] = acc[db][j][r] * invl[j];
}

// ---------------------------------------------------------------------------
extern "C" void kernel_launch(void* const* d_in, const int* in_sizes, int n_in,
                              void* d_out, int out_size, void* d_ws, size_t ws_size,
                              hipStream_t stream)
{
  (void)in_sizes; (void)n_in; (void)out_size; (void)ws_size;
  const float* desc1 = (const float*)d_in[0];
  const float* desc2 = (const float*)d_in[1];
  const float* wvv   = (const float*)d_in[2];
  const float* Wq  = (const float*)d_in[3];  const float* bq  = (const float*)d_in[4];
  const float* Wk  = (const float*)d_in[5];  const float* bk  = (const float*)d_in[6];
  const float* Wv  = (const float*)d_in[7];  const float* bv  = (const float*)d_in[8];
  const float* Wm  = (const float*)d_in[9];  const float* bm  = (const float*)d_in[10];
  const float* Wc1 = (const float*)d_in[11]; const float* bc1 = (const float*)d_in[12];
  const float* bng = (const float*)d_in[13]; const float* bnb = (const float*)d_in[14];
  const float* bnm = (const float*)d_in[15]; const float* bnv = (const float*)d_in[16];
  const float* Wc2 = (const float*)d_in[17]; const float* bc2 = (const float*)d_in[18];
  float* out = (float*)d_out;

  // Workspace (58.7 MB peak, aliased by liveness):
  //  bytes [0,8.4)    Qt bf16   — dead after attn
  //  bytes [8.4,16.8) Kt bf16   — dead after attn
  //  bytes [16.8,25.2) Vb bf16  — dead after attn
  //  floats @3*BCN/2: attn f32 (16.8 MB) — dead after mout
  //  floats @3*BCN/2+BCN: mout f32 (16.8 MB) — dead after h
  //  h f32 (33.6 MB) @0 — overlaps Qt/Kt/Vb/attn (all dead then)
  unsigned short* wsu = (unsigned short*)d_ws;
  float*          wsf = (float*)d_ws;
  unsigned short* Qt = wsu;
  unsigned short* Ktp = wsu + BCN;
  unsigned short* Vb = wsu + 2 * BCN;
  float* attn = wsf + (3 * BCN) / 2;
  float* mout = attn + BCN;
  float* h    = wsf;

  dim3 blk(256);
  // Qt = bf16(0.125*(Wq*desc1+bq)) in [bh][n][d]
  proj_kernel<256,0,256,false,false,false,2><<<dim3(Nn/256, 32, Bb), blk, 0, stream>>>(
      desc1, nullptr, Wq, bq, nullptr, nullptr,nullptr,nullptr,nullptr, nullptr, Qt, Nn, 0.125f);
  // Kt = bf16(Wk*desc2+bk) in [bh][m][d]
  proj_kernel<256,0,256,false,false,false,2><<<dim3(Mm/256, 32, Bb), blk, 0, stream>>>(
      desc2, nullptr, Wk, bk, nullptr, nullptr,nullptr,nullptr,nullptr, nullptr, Ktp, Mm, 1.0f);
  // Vb = bf16((Wv*desc2+bv)*weight_v) in [bh][d][m] (== [b][c][m])
  proj_kernel<256,0,256,true,false,false,1><<<dim3(Mm/256, 32, Bb), blk, 0, stream>>>(
      desc2, nullptr, Wv, bv, wvv, nullptr,nullptr,nullptr,nullptr, nullptr, Vb, Mm, 1.0f);
  // attn = flash-MFMA
  attn_mfma_kernel<<<dim3(512), blk, 0, stream>>>(Qt, Ktp, Vb, attn);
  // mout = Wm*attn + bm (f32)
  proj_kernel<256,0,256,false,false,false,0><<<dim3(Nn/256, 32, Bb), blk, 0, stream>>>(
      attn, nullptr, Wm, bm, nullptr, nullptr,nullptr,nullptr,nullptr, nullptr, mout, Nn, 1.0f);
  // h = relu(BN(Wc1*[desc1; mout] + bc1))
  proj_kernel<256,256,512,false,true,false,0><<<dim3(Nn/256, 64, Bb), blk, 0, stream>>>(
      desc1, mout, Wc1, bc1, nullptr, bng,bnb,bnm,bnv, nullptr, h, Nn, 1.0f);
  // out = desc1 + Wc2*h + bc2
  proj_kernel<512,0,256,false,false,true,0><<<dim3(Nn/256, 32, Bb), blk, 0, stream>>>(
      h, nullptr, Wc2, bc2, nullptr, nullptr,nullptr,nullptr,nullptr, desc1, out, Nn, 1.0f);
}

// Round 7
// 299.316 us; speedup vs baseline: 3.7357x; 2.1868x over previous
//
#include <hip/hip_runtime.h>
#include <hip/hip_bf16.h>
#include <math.h>

// Problem constants (fixed by the reference).
constexpr int Bb = 8;
constexpr int Cc = 256;
constexpr int Hh = 4;
constexpr int Nn = 2048;
constexpr int Mm = 2048;
constexpr size_t BCN = (size_t)Bb * Cc * Nn;   // 4,194,304 elements

typedef __attribute__((ext_vector_type(8))) short short8;
typedef __attribute__((ext_vector_type(4))) float f32x4;

__device__ __forceinline__ unsigned short bfu(float x) {
  __hip_bfloat16 b = __float2bfloat16(x);        // RNE
  return __builtin_bit_cast(unsigned short, b);
}

__device__ __forceinline__ void gload16(const unsigned short* g, unsigned short* l) {
  __builtin_amdgcn_global_load_lds(
      (const __attribute__((address_space(1))) unsigned int*)g,
      (__attribute__((address_space(3))) unsigned int*)l, 16, 0, 0);
}

// ---------------------------------------------------------------------------
// Weight quantization: f32 -> bf16 (Wq scaled by 0.125). One launch, 6 segs.
// ---------------------------------------------------------------------------
__global__ __launch_bounds__(256) void quantw_kernel(
    const float* __restrict__ s0, const float* __restrict__ s1,
    const float* __restrict__ s2, const float* __restrict__ s3,
    const float* __restrict__ s4, const float* __restrict__ s5,
    unsigned short* __restrict__ d0, unsigned short* __restrict__ d1,
    unsigned short* __restrict__ d2, unsigned short* __restrict__ d3,
    unsigned short* __restrict__ d4, unsigned short* __restrict__ d5)
{
  const int seg = blockIdx.y;
  const float* s; unsigned short* d; int cnt; float sc = 1.f;
  switch (seg) {
    case 0: s = s0; d = d0; cnt = 65536;  sc = 0.125f; break;
    case 1: s = s1; d = d1; cnt = 65536;  break;
    case 2: s = s2; d = d2; cnt = 65536;  break;
    case 3: s = s3; d = d3; cnt = 65536;  break;
    case 4: s = s4; d = d4; cnt = 262144; break;
    default: s = s5; d = d5; cnt = 131072; break;
  }
  for (int i = blockIdx.x * 256 + threadIdx.x; i < cnt / 4; i += 64 * 256) {
    float4 v = ((const float4*)s)[i];
    unsigned int lo = bfu(v.x * sc) | ((unsigned int)bfu(v.y * sc) << 16);
    unsigned int hi = bfu(v.z * sc) | ((unsigned int)bfu(v.w * sc) << 16);
    ((uint2*)d)[i] = make_uint2(lo, hi);
  }
}

// ---------------------------------------------------------------------------
// Transpose+quantize: desc [b][256][2048] f32 -> [b][2048][256] bf16.
// blockIdx.z: 0-7 desc1, 8-15 desc2. 64x64 tiles via padded LDS.
// ---------------------------------------------------------------------------
__global__ __launch_bounds__(256) void trans_kernel(
    const float* __restrict__ S1, const float* __restrict__ S2,
    unsigned short* __restrict__ D1, unsigned short* __restrict__ D2)
{
  __shared__ float T[64][65];
  const int z = blockIdx.z, b = z & 7;
  const float* S = (z >> 3) ? S2 : S1;
  unsigned short* D = (z >> 3) ? D2 : D1;
  const int n0 = blockIdx.x * 64, c0 = blockIdx.y * 64;
  const int t = threadIdx.x, t4 = t >> 6, tl = t & 63;

  #pragma unroll
  for (int r = 0; r < 16; ++r) {
    int cl = r * 4 + t4;
    T[cl][tl] = S[((size_t)b * 256 + c0 + cl) * 2048 + n0 + tl];
  }
  __syncthreads();
  #pragma unroll
  for (int r = 0; r < 16; ++r) {
    int nl = r * 4 + t4;
    D[((size_t)b * 2048 + n0 + nl) * 256 + c0 + tl] = bfu(T[tl][nl]);
  }
}

// ---------------------------------------------------------------------------
// bf16 MFMA GEMM: C[o][n] = sum_k W[o][k] * X[b][n][k]  (per b).
// 128x128 tile, BK=64, 4 waves (2x2 of 64x64), global_load_lds staging with
// K-group XOR swizzle (pre-swizzled global source, linear LDS, swizzled read).
// EPI: 0 = Q/K (transposed out, bf16 [b*H+h][n][64], bias*oscale)
//      1 = V   (normal out, bf16 [b][o][m], (acc+bias)*weight_v[b][m])
//      2 = M   (transposed out, bf16 [b][n][256], +bias)
//      3 = C1  (transposed out, bf16 [b][n][512], BN+ReLU epilogue)
//      4 = C2  (normal out, f32 [b][o][n], +bias+residual)
// ---------------------------------------------------------------------------
template<int K1, int K2, int COUT, int EPI>
__global__ __launch_bounds__(256) void gemm_kernel(
    const unsigned short* __restrict__ Wb,
    const unsigned short* __restrict__ X1, const unsigned short* __restrict__ X2,
    const float* __restrict__ bias,
    const float* __restrict__ p0, const float* __restrict__ p1,
    const float* __restrict__ p2, const float* __restrict__ p3,
    void* __restrict__ Yv, float oscale)
{
  constexpr int KT = K1 + K2;
  constexpr bool TRANS = (EPI == 0 || EPI == 2 || EPI == 3);
  __shared__ unsigned short lds[2 * 128 * 64];
  unsigned short* Wl = lds;
  unsigned short* Xl = lds + 128 * 64;

  const int t = threadIdx.x;
  const int w = t >> 6, l = t & 63;
  const int c = l & 15, h4 = l >> 4;
  const int n0 = blockIdx.x * 128;
  const int o0 = blockIdx.y * 128;
  const int b  = blockIdx.z;
  const int wo = (w & 1) * 64, wn = (w >> 1) * 64;

  // staging coordinates: chunk q covers rows q*32..q*32+31
  const int r8  = t >> 3;               // row within chunk
  const int kgx = (t & 7) ^ (r8 & 7);   // pre-swizzled k-group (involution)

  const unsigned short* Xb1 = X1 + (size_t)b * 2048 * K1;

  f32x4 acc[4][4] = {};

  #pragma unroll 1
  for (int kt = 0; kt < KT / 64; ++kt) {
    __syncthreads();                    // previous iter's reads complete
    #pragma unroll
    for (int q = 0; q < 4; ++q) {
      int row = q * 32 + r8;
      gload16(Wb + (size_t)(o0 + row) * KT + kt * 64 + kgx * 8,
              Wl + q * 2048 + w * 512);
      const unsigned short* src;
      if constexpr (K2 == 0) {
        src = Xb1 + (size_t)(n0 + row) * K1 + kt * 64 + kgx * 8;
      } else {
        src = (kt * 64 < K1)
          ? Xb1 + (size_t)(n0 + row) * K1 + kt * 64 + kgx * 8
          : X2 + ((size_t)b * 2048 + n0 + row) * K2 + (kt * 64 - K1) + kgx * 8;
      }
      gload16(src, Xl + q * 2048 + w * 512);
    }
    __syncthreads();                    // staging complete (vmcnt(0) at barrier)

    #pragma unroll
    for (int kk = 0; kk < 2; ++kk) {
      short8 wf[4], xf[4];
      #pragma unroll
      for (int f = 0; f < 4; ++f) {
        int row = wo + f * 16 + c;
        wf[f] = *(const short8*)((const char*)Wl + row * 128 + (((kk * 4 + h4) ^ (row & 7)) << 4));
      }
      #pragma unroll
      for (int f = 0; f < 4; ++f) {
        int row = wn + f * 16 + c;
        xf[f] = *(const short8*)((const char*)Xl + row * 128 + (((kk * 4 + h4) ^ (row & 7)) << 4));
      }
      #pragma unroll
      for (int i = 0; i < 4; ++i)
        #pragma unroll
        for (int j = 0; j < 4; ++j) {
          if constexpr (TRANS)
            acc[i][j] = __builtin_amdgcn_mfma_f32_16x16x32_bf16(xf[i], wf[j], acc[i][j], 0, 0, 0);
          else
            acc[i][j] = __builtin_amdgcn_mfma_f32_16x16x32_bf16(wf[i], xf[j], acc[i][j], 0, 0, 0);
        }
    }
  }

  // ---------------- epilogues ----------------
  if constexpr (EPI == 0) {             // Qt/Kt: [b*H+h][n][64] bf16
    unsigned short* Y = (unsigned short*)Yv;
    #pragma unroll
    for (int j = 0; j < 4; ++j) {       // o frags (lane cols)
      int og = o0 + wo + j * 16 + c;
      float bb = bias[og] * oscale;
      int hh = og >> 6, d = og & 63;
      unsigned short* Yp = Y + (((size_t)b * Hh + hh) * 2048) * 64 + d;
      #pragma unroll
      for (int i = 0; i < 4; ++i) {     // n frags (rows)
        #pragma unroll
        for (int r = 0; r < 4; ++r) {
          int ng = n0 + wn + i * 16 + h4 * 4 + r;
          Yp[(size_t)ng * 64] = bfu(acc[i][j][r] + bb);
        }
      }
    }
  } else if constexpr (EPI == 2) {      // MoutT: [b][n][256] bf16
    unsigned short* Y = (unsigned short*)Yv;
    #pragma unroll
    for (int j = 0; j < 4; ++j) {
      int og = o0 + wo + j * 16 + c;
      float bb = bias[og];
      #pragma unroll
      for (int i = 0; i < 4; ++i)
        #pragma unroll
        for (int r = 0; r < 4; ++r) {
          int ng = n0 + wn + i * 16 + h4 * 4 + r;
          Y[((size_t)b * 2048 + ng) * 256 + og] = bfu(acc[i][j][r] + bb);
        }
    }
  } else if constexpr (EPI == 3) {      // HT: [b][n][512] bf16, BN+ReLU
    unsigned short* Y = (unsigned short*)Yv;
    #pragma unroll
    for (int j = 0; j < 4; ++j) {
      int og = o0 + wo + j * 16 + c;
      float bb  = bias[og];
      float inv = p0[og] / sqrtf(p3[og] + 1e-5f);
      float add = p1[og] - p2[og] * inv;
      #pragma unroll
      for (int i = 0; i < 4; ++i)
        #pragma unroll
        for (int r = 0; r < 4; ++r) {
          int ng = n0 + wn + i * 16 + h4 * 4 + r;
          float v = fmaxf((acc[i][j][r] + bb) * inv + add, 0.f);
          Y[((size_t)b * 2048 + ng) * 512 + og] = bfu(v);
        }
    }
  } else if constexpr (EPI == 1) {      // Vb: [b][o][m] bf16, *weight_v
    unsigned short* Y = (unsigned short*)Yv;
    #pragma unroll
    for (int j = 0; j < 4; ++j) {       // n (=m) frags, lane cols
      int mg = n0 + wn + j * 16 + c;
      float sc = p0[(size_t)b * 2048 + mg];
      #pragma unroll
      for (int i = 0; i < 4; ++i)       // o frags, rows
        #pragma unroll
        for (int r = 0; r < 4; ++r) {
          int og = o0 + wo + i * 16 + h4 * 4 + r;
          Y[((size_t)b * 256 + og) * 2048 + mg] = bfu((acc[i][j][r] + bias[og]) * sc);
        }
    }
  } else {                              // out: [b][o][n] f32, +bias+residual
    float* Y = (float*)Yv;
    #pragma unroll
    for (int j = 0; j < 4; ++j) {
      int ng = n0 + wn + j * 16 + c;
      #pragma unroll
      for (int i = 0; i < 4; ++i)
        #pragma unroll
        for (int r = 0; r < 4; ++r) {
          int og = o0 + wo + i * 16 + h4 * 4 + r;
          size_t idx = ((size_t)b * 256 + og) * 2048 + ng;
          Y[idx] = acc[i][j][r] + bias[og] + p0[idx];
        }
    }
  }
}

// ---------------------------------------------------------------------------
// MFMA flash attention (unchanged core; epilogue writes Ot [b][n][256] bf16).
// ---------------------------------------------------------------------------
__global__ __launch_bounds__(256) void attn_mfma_kernel(
    const unsigned short* __restrict__ Qt, const unsigned short* __restrict__ Kt,
    const unsigned short* __restrict__ Vb, unsigned short* __restrict__ Ot)
{
  const int id  = blockIdx.x;
  const int xcd = id & 7;
  const int s8  = id >> 3;
  const int bh  = xcd + 8 * (s8 >> 4);
  const int nb  = s8 & 15;
  const int wv  = threadIdx.x >> 6;
  const int l   = threadIdx.x & 63;
  const int c   = l & 15;
  const int h   = l >> 4;
  const int n0  = nb * 128 + wv * 32;

  const unsigned short* Qw = Qt + ((size_t)bh * Nn + n0) * 64;
  const unsigned short* Kb = Kt + (size_t)bh * Mm * 64;
  const unsigned short* Vw = Vb + (size_t)bh * 64 * Mm;

  __shared__ unsigned short Pl[4][32 * 64];
  char* P = (char*)Pl[wv];

  short8 qf[2][2];
  #pragma unroll
  for (int j = 0; j < 2; ++j)
    #pragma unroll
    for (int ks = 0; ks < 2; ++ks)
      qf[j][ks] = *(const short8*)(Qw + ((size_t)(j*16 + c)) * 64 + ks*32 + h*8);

  f32x4 acc[4][2];
  #pragma unroll
  for (int d = 0; d < 4; ++d)
    #pragma unroll
    for (int j = 0; j < 2; ++j) acc[d][j] = (f32x4){0.f,0.f,0.f,0.f};
  float rowM[2] = {-1e30f, -1e30f};
  float rowL[2] = {0.f, 0.f};

  #pragma unroll 1
  for (int m0 = 0; m0 < Mm; m0 += 64) {
    short8 kf[4][2];
    #pragma unroll
    for (int g = 0; g < 4; ++g)
      #pragma unroll
      for (int ks = 0; ks < 2; ++ks)
        kf[g][ks] = *(const short8*)(Kb + ((size_t)(m0 + g*16 + c)) * 64 + ks*32 + h*8);

    f32x4 sc4[4][2];
    #pragma unroll
    for (int g = 0; g < 4; ++g)
      #pragma unroll
      for (int j = 0; j < 2; ++j) {
        f32x4 z = (f32x4){0.f,0.f,0.f,0.f};
        z = __builtin_amdgcn_mfma_f32_16x16x32_bf16(kf[g][0], qf[j][0], z, 0, 0, 0);
        z = __builtin_amdgcn_mfma_f32_16x16x32_bf16(kf[g][1], qf[j][1], z, 0, 0, 0);
        sc4[g][j] = z;
      }

    short8 vf[4][2];
    #pragma unroll
    for (int db = 0; db < 4; ++db)
      #pragma unroll
      for (int ks = 0; ks < 2; ++ks)
        vf[db][ks] = *(const short8*)(Vw + ((size_t)(db*16 + c)) * Mm + m0 + ks*32 + h*8);

    #pragma unroll
    for (int j = 0; j < 2; ++j) {
      float mx = -1e30f;
      #pragma unroll
      for (int g = 0; g < 4; ++g)
        #pragma unroll
        for (int r = 0; r < 4; ++r) mx = fmaxf(mx, sc4[g][j][r]);
      mx = fmaxf(mx, __shfl_xor(mx, 16));
      mx = fmaxf(mx, __shfl_xor(mx, 32));
      float nm = fmaxf(rowM[j], mx);
      float corr = __expf(rowM[j] - nm);
      rowM[j] = nm;
      float sum = 0.f;
      #pragma unroll
      for (int g = 0; g < 4; ++g) {
        #pragma unroll
        for (int r = 0; r < 4; ++r) {
          float e = __expf(sc4[g][j][r] - nm);
          sc4[g][j][r] = e;
          sum += e;
        }
      }
      sum += __shfl_xor(sum, 16);
      sum += __shfl_xor(sum, 32);
      rowL[j] = rowL[j] * corr + sum;
      #pragma unroll
      for (int db = 0; db < 4; ++db)
        #pragma unroll
        for (int r = 0; r < 4; ++r) acc[db][j][r] *= corr;

      #pragma unroll
      for (int g = 0; g < 4; ++g) {
        unsigned int lo = ((unsigned int)bfu(sc4[g][j][1]) << 16) | bfu(sc4[g][j][0]);
        unsigned int hi = ((unsigned int)bfu(sc4[g][j][3]) << 16) | bfu(sc4[g][j][2]);
        int off = (j*16 + c) * 128 + g*32 + h*8;
        off ^= (c & 7) << 4;
        *(uint2*)(P + off) = make_uint2(lo, hi);
      }
    }

    #pragma unroll
    for (int j = 0; j < 2; ++j) {
      short8 pf[2];
      #pragma unroll
      for (int ks = 0; ks < 2; ++ks) {
        int off = (j*16 + c) * 128 + ks*64 + h*16;
        off ^= (c & 7) << 4;
        pf[ks] = *(const short8*)(P + off);
      }
      #pragma unroll
      for (int db = 0; db < 4; ++db) {
        acc[db][j] = __builtin_amdgcn_mfma_f32_16x16x32_bf16(vf[db][0], pf[0], acc[db][j], 0, 0, 0);
        acc[db][j] = __builtin_amdgcn_mfma_f32_16x16x32_bf16(vf[db][1], pf[1], acc[db][j], 0, 0, 0);
      }
    }
  }

  const float invl[2] = {1.f / rowL[0], 1.f / rowL[1]};
  // Ot[b][n][256] bf16, c-index = (bh&3)*64 + db*16 + h*4 + r  -> 8B stores
  unsigned short* Ob = Ot + ((size_t)(bh >> 2) * Nn) * 256 + (bh & 3) * 64;
  #pragma unroll
  for (int db = 0; db < 4; ++db)
    #pragma unroll
    for (int j = 0; j < 2; ++j) {
      unsigned int lo = ((unsigned int)bfu(acc[db][j][1] * invl[j]) << 16) | bfu(acc[db][j][0] * invl[j]);
      unsigned int hi = ((unsigned int)bfu(acc[db][j][3] * invl[j]) << 16) | bfu(acc[db][j][2] * invl[j]);
      *(uint2*)(Ob + (size_t)(n0 + j*16 + c) * 256 + db*16 + h*4) = make_uint2(lo, hi);
    }
}

// ---------------------------------------------------------------------------
extern "C" void kernel_launch(void* const* d_in, const int* in_sizes, int n_in,
                              void* d_out, int out_size, void* d_ws, size_t ws_size,
                              hipStream_t stream)
{
  (void)in_sizes; (void)n_in; (void)out_size; (void)ws_size;
  const float* desc1 = (const float*)d_in[0];
  const float* desc2 = (const float*)d_in[1];
  const float* wvv   = (const float*)d_in[2];
  const float* Wq  = (const float*)d_in[3];  const float* bq  = (const float*)d_in[4];
  const float* Wk  = (const float*)d_in[5];  const float* bk  = (const float*)d_in[6];
  const float* Wv  = (const float*)d_in[7];  const float* bv  = (const float*)d_in[8];
  const float* Wm  = (const float*)d_in[9];  const float* bm  = (const float*)d_in[10];
  const float* Wc1 = (const float*)d_in[11]; const float* bc1 = (const float*)d_in[12];
  const float* bng = (const float*)d_in[13]; const float* bnb = (const float*)d_in[14];
  const float* bnm = (const float*)d_in[15]; const float* bnv = (const float*)d_in[16];
  const float* Wc2 = (const float*)d_in[17]; const float* bc2 = (const float*)d_in[18];
  float* out = (float*)d_out;

  // Workspace (ushort units), 43.3 MB peak, aliased by liveness:
  //  [0]      D1t  (live to c1)
  //  [1]      D2t  -> Ot      (D2t dead after v-gemm)
  //  [2]      Qt   -> MoutT   (Qt dead after attn)
  //  [3],[4]  Kt,Vb -> HT(2x) (dead after attn)
  //  [5]      bf16 weights
  unsigned short* u = (unsigned short*)d_ws;
  unsigned short* D1t  = u;
  unsigned short* D2t  = u + BCN;
  unsigned short* Qt   = u + 2 * BCN;
  unsigned short* Kt   = u + 3 * BCN;
  unsigned short* Vbb  = u + 4 * BCN;
  unsigned short* Ot    = D2t;
  unsigned short* MoutT = Qt;
  unsigned short* HT    = Kt;          // 2*BCN
  unsigned short* Wqb  = u + 5 * BCN;
  unsigned short* Wkb  = Wqb + 65536;
  unsigned short* Wvb  = Wkb + 65536;
  unsigned short* Wmb  = Wvb + 65536;
  unsigned short* Wc1b = Wmb + 65536;
  unsigned short* Wc2b = Wc1b + 262144;

  dim3 blk(256);
  quantw_kernel<<<dim3(64, 6), blk, 0, stream>>>(
      Wq, Wk, Wv, Wm, Wc1, Wc2, Wqb, Wkb, Wvb, Wmb, Wc1b, Wc2b);
  trans_kernel<<<dim3(32, 4, 16), blk, 0, stream>>>(desc1, desc2, D1t, D2t);

  // Qt = [bh][n][64] bf16 of 0.125*(Wq desc1 + bq)
  gemm_kernel<256,0,256,0><<<dim3(16, 2, Bb), blk, 0, stream>>>(
      Wqb, D1t, nullptr, bq, nullptr,nullptr,nullptr,nullptr, Qt, 0.125f);
  // Kt = [bh][m][64]
  gemm_kernel<256,0,256,0><<<dim3(16, 2, Bb), blk, 0, stream>>>(
      Wkb, D2t, nullptr, bk, nullptr,nullptr,nullptr,nullptr, Kt, 1.0f);
  // Vb = [b][o][m] * weight_v
  gemm_kernel<256,0,256,1><<<dim3(16, 2, Bb), blk, 0, stream>>>(
      Wvb, D2t, nullptr, bv, wvv,nullptr,nullptr,nullptr, Vbb, 1.0f);
  // attention -> Ot [b][n][256] bf16
  attn_mfma_kernel<<<dim3(512), blk, 0, stream>>>(Qt, Kt, Vbb, Ot);
  // MoutT = [b][n][256] bf16 of (Wm attn + bm)
  gemm_kernel<256,0,256,2><<<dim3(16, 2, Bb), blk, 0, stream>>>(
      Wmb, Ot, nullptr, bm, nullptr,nullptr,nullptr,nullptr, MoutT, 1.0f);
  // HT = [b][n][512] bf16 of relu(BN(Wc1 [desc1; mout] + bc1))
  gemm_kernel<256,256,512,3><<<dim3(16, 4, Bb), blk, 0, stream>>>(
      Wc1b, D1t, MoutT, bc1, bng,bnb,bnm,bnv, HT, 1.0f);
  // out = desc1 + Wc2 h + bc2  (f32)
  gemm_kernel<512,0,256,4><<<dim3(16, 2, Bb), blk, 0, stream>>>(
      Wc2b, HT, nullptr, bc2, desc1,nullptr,nullptr,nullptr, out, 1.0f);
}